// Round 3
// baseline (636.012 us; speedup 1.0000x reference)
//
#include <hip/hip_runtime.h>
#include <cstdint>
#include <cstddef>

#define BB 64
#define TT 512
#define DD 1024
#define NTAG 64
#define SCORES_ELEMS (BB * TT * NTAG)      // 2097152
#define TAGS_OFF SCORES_ELEMS              // 2097152
#define LOSS_OFF (SCORES_ELEMS + BB * TT)  // 2130920

// ---------------- DPP wave64 reductions ----------------
__device__ __forceinline__ float dpp_red_max(float v) {
  int x;
  x = __builtin_amdgcn_update_dpp(__float_as_int(v), __float_as_int(v), 0x111, 0xf, 0xf, false);
  v = fmaxf(v, __int_as_float(x));
  x = __builtin_amdgcn_update_dpp(__float_as_int(v), __float_as_int(v), 0x112, 0xf, 0xf, false);
  v = fmaxf(v, __int_as_float(x));
  x = __builtin_amdgcn_update_dpp(__float_as_int(v), __float_as_int(v), 0x114, 0xf, 0xf, false);
  v = fmaxf(v, __int_as_float(x));
  x = __builtin_amdgcn_update_dpp(__float_as_int(v), __float_as_int(v), 0x118, 0xf, 0xf, false);
  v = fmaxf(v, __int_as_float(x));
  x = __builtin_amdgcn_update_dpp(__float_as_int(v), __float_as_int(v), 0x142, 0xa, 0xf, false);
  v = fmaxf(v, __int_as_float(x));
  x = __builtin_amdgcn_update_dpp(__float_as_int(v), __float_as_int(v), 0x143, 0xc, 0xf, false);
  v = fmaxf(v, __int_as_float(x));
  return __int_as_float(__builtin_amdgcn_readlane(__float_as_int(v), 63));
}

__device__ __forceinline__ float dpp_red_sum(float v) {
  int x;
  x = __builtin_amdgcn_update_dpp(__float_as_int(v), __float_as_int(v), 0x111, 0xf, 0xf, false);
  v = v + __int_as_float(x);
  x = __builtin_amdgcn_update_dpp(__float_as_int(v), __float_as_int(v), 0x112, 0xf, 0xf, false);
  v = v + __int_as_float(x);
  x = __builtin_amdgcn_update_dpp(__float_as_int(v), __float_as_int(v), 0x114, 0xf, 0xf, false);
  v = v + __int_as_float(x);
  x = __builtin_amdgcn_update_dpp(__float_as_int(v), __float_as_int(v), 0x118, 0xf, 0xf, false);
  v = v + __int_as_float(x);
  x = __builtin_amdgcn_update_dpp(__float_as_int(v), __float_as_int(v), 0x142, 0xa, 0xf, false);
  v = v + __int_as_float(x);
  x = __builtin_amdgcn_update_dpp(__float_as_int(v), __float_as_int(v), 0x143, 0xc, 0xf, false);
  v = v + __int_as_float(x);
  return __int_as_float(__builtin_amdgcn_readlane(__float_as_int(v), 63));
}

// ---------------- Kernel 1: scores = (X @ W + b) * mask ----------------
// 512 blocks x 256 thr. Block tile 64 rows x 64 cols. Each wave owns a
// K-quarter (256 k) -- no barriers in the main loop. Lane computes an 8x8
// register tile: per k, 4 ds_read_b128 feed 64 FMAs (vs 4 in the old
// broadcast design). Global->LDS via register-prefetch double buffer.
// Wave partials combined with ds_add_f32 (LDS atomics).
__global__ __launch_bounds__(256) void gemm_scores(
    const float* __restrict__ X, const int* __restrict__ mask,
    const float* __restrict__ W, const float* __restrict__ bias,
    float* __restrict__ scores) {
  __shared__ float smem[12288];  // 48KB: [0,8192) wave staging (2048/wave), [8192,12288) psum
  const int tid = threadIdx.x;
  const int lane = tid & 63;
  const int wv = tid >> 6;
  const int row0 = blockIdx.x * 64;
  const int kbase = wv * 256;
  float* psum = smem + 8192;

  // zero psum (before any atomics)
  {
    const float4 z4 = make_float4(0.f, 0.f, 0.f, 0.f);
#pragma unroll
    for (int g = 0; g < 4; ++g)
      *reinterpret_cast<float4*>(&psum[tid * 16 + g * 4]) = z4;
  }
  __syncthreads();

  float* smx = smem + wv * 2048;         // xT[16][64]: smx[k*64+row]
  float* smw = smem + wv * 2048 + 1024;  // wt[16][64]: smw[k*64+col]

  const int lr = lane & 7;
  const int lc = lane >> 3;
  const int xrow = lane >> 2;       // 0..15
  const int xkk = (lane & 3) * 4;   // 0,4,8,12

  float acc[8][8];
#pragma unroll
  for (int i = 0; i < 8; ++i)
#pragma unroll
    for (int j = 0; j < 8; ++j) acc[i][j] = 0.f;

  const float* Xb = X + (size_t)row0 * DD + kbase;
  const float* Wb = W + (size_t)kbase * NTAG;

  float4 px[4], pw[4];
#pragma unroll
  for (int p = 0; p < 4; ++p) {
    px[p] = *reinterpret_cast<const float4*>(Xb + (size_t)(xrow + p * 16) * DD + xkk);
    pw[p] = *reinterpret_cast<const float4*>(Wb + p * 256 + lane * 4);
  }

  for (int c = 0; c < 16; ++c) {
    // stage prefetched regs -> LDS (same-wave in-order; no barrier needed)
#pragma unroll
    for (int p = 0; p < 4; ++p) {
      const int r = xrow + p * 16;
      smx[(xkk + 0) * 64 + r] = px[p].x;
      smx[(xkk + 1) * 64 + r] = px[p].y;
      smx[(xkk + 2) * 64 + r] = px[p].z;
      smx[(xkk + 3) * 64 + r] = px[p].w;
      *reinterpret_cast<float4*>(&smw[p * 256 + lane * 4]) = pw[p];
    }
    // prefetch next chunk (clamped reload of chunk 0 on last iter; in-bounds)
    const int cn = (c < 15) ? (c + 1) : 0;
#pragma unroll
    for (int p = 0; p < 4; ++p) {
      px[p] = *reinterpret_cast<const float4*>(
          Xb + (size_t)(xrow + p * 16) * DD + cn * 16 + xkk);
      pw[p] = *reinterpret_cast<const float4*>(Wb + cn * 1024 + p * 256 + lane * 4);
    }
    // compute on staged chunk
#pragma unroll
    for (int k = 0; k < 16; ++k) {
      const float4 xa = *reinterpret_cast<const float4*>(&smx[k * 64 + lr * 8]);
      const float4 xb = *reinterpret_cast<const float4*>(&smx[k * 64 + lr * 8 + 4]);
      const float4 wa = *reinterpret_cast<const float4*>(&smw[k * 64 + lc * 8]);
      const float4 wb = *reinterpret_cast<const float4*>(&smw[k * 64 + lc * 8 + 4]);
      const float xv[8] = {xa.x, xa.y, xa.z, xa.w, xb.x, xb.y, xb.z, xb.w};
      const float wvv[8] = {wa.x, wa.y, wa.z, wa.w, wb.x, wb.y, wb.z, wb.w};
#pragma unroll
      for (int i = 0; i < 8; ++i)
#pragma unroll
        for (int j = 0; j < 8; ++j)
          acc[i][j] = fmaf(xv[i], wvv[j], acc[i][j]);
    }
  }

  // combine wave partials (fp-order nondeterminism ~1ulp, irrelevant)
#pragma unroll
  for (int i = 0; i < 8; ++i) {
    const int row = lr * 8 + i;
#pragma unroll
    for (int j = 0; j < 8; ++j)
      atomicAdd(&psum[row * 64 + lc * 8 + j], acc[i][j]);
  }
  __syncthreads();

  // epilogue: bias + mask, coalesced float4 stores
  const int f = tid * 16;
  const int row = f >> 6;  // tid/4; 16 floats stay within one 64-col row
  const float mf = (float)mask[row0 + row];
#pragma unroll
  for (int g = 0; g < 4; ++g) {
    const int idx = f + g * 4;
    const int col = idx & 63;
    const float4 p = *reinterpret_cast<float4*>(&psum[idx]);
    const float4 b4 = *reinterpret_cast<const float4*>(&bias[col]);
    float4 o;
    o.x = (p.x + b4.x) * mf;
    o.y = (p.y + b4.y) * mf;
    o.z = (p.z + b4.z) * mf;
    o.w = (p.w + b4.w) * mf;
    *reinterpret_cast<float4*>(&scores[(size_t)(row0 + row) * 64 + col]) = o;
  }
}

// ---------------- Kernel 2: CRF (viterbi + log-partition + gold) ----------------
__global__ __launch_bounds__(64) void crf_kernel(
    const float* __restrict__ scores, const int* __restrict__ mask,
    const int* __restrict__ labels, const float* __restrict__ trans,
    const float* __restrict__ startv, const float* __restrict__ endv,
    float* __restrict__ out_tags, float* __restrict__ ws_alpha,
    float* __restrict__ ws_loss) {
  const int lane = threadIdx.x;
  const int role = blockIdx.x >> 6;
  const int b = blockIdx.x & 63;
  const float* sc = scores + (size_t)b * TT * NTAG;
  const int* maskb = mask + b * TT;

  if (role == 0) {
    // ---------------- Viterbi ----------------
    __shared__ float transR[NTAG * 65];  // row-major, stride 65: conflict-free backtrack reads
    __shared__ __align__(16) float alpha_lds[NTAG];
    __shared__ int tagbuf[TT];
    float tcol[NTAG];  // tcol[i] = trans[i][lane]
#pragma unroll
    for (int i = 0; i < NTAG; ++i) {
      const float v = trans[(size_t)i * NTAG + lane];
      tcol[i] = v;
      transR[i * 65 + lane] = v;
    }
    float valpha = startv[lane] + sc[lane];
    float* wsA = ws_alpha + (size_t)b * (TT - 1) * NTAG;

    float e0 = sc[1 * NTAG + lane], e1 = sc[2 * NTAG + lane];
    float e2 = sc[3 * NTAG + lane], e3 = sc[4 * NTAG + lane];
    int k0 = maskb[1], k1 = maskb[2], k2 = maskb[3], k3 = maskb[4];

    for (int t = 1; t < TT; ++t) {
      alpha_lds[lane] = valpha;
      wsA[(size_t)(t - 1) * NTAG + lane] = valpha;
      const float emit = e0;
      const int m = k0;
      const int tp = (t + 4 < TT) ? (t + 4) : (TT - 1);
      e0 = e1; e1 = e2; e2 = e3;
      e3 = sc[(size_t)tp * NTAG + lane];
      k0 = k1; k1 = k2; k2 = k3;
      k3 = maskb[tp];

      float best = -3.4e38f;
#pragma unroll
      for (int i = 0; i < NTAG; i += 4) {
        const float4 a4 = *reinterpret_cast<const float4*>(&alpha_lds[i]);
        const float c0 = a4.x + tcol[i + 0];
        const float c1 = a4.y + tcol[i + 1];
        const float c2 = a4.z + tcol[i + 2];
        const float c3 = a4.w + tcol[i + 3];
        best = fmaxf(best, fmaxf(fmaxf(c0, c1), fmaxf(c2, c3)));
      }
      valpha = m ? (best + emit) : valpha;
    }

    const float fin = valpha + endv[lane];
    const float mx = dpp_red_max(fin);
    int jcur = (int)__builtin_ctzll(__ballot(fin == mx));
    if (lane == 0) tagbuf[TT - 1] = jcur;

    // backtrack: fmax is order-independent, so recomputed max == forward max
    float aw0 = wsA[(size_t)(TT - 2) * NTAG + lane];
    float aw1 = wsA[(size_t)(TT - 3) * NTAG + lane];
    int mk0 = maskb[TT - 1], mk1 = maskb[TT - 2];
    for (int s = TT - 2; s >= 0; --s) {
      const float a_cur = aw0;
      aw0 = aw1;
      const int i2 = (s >= 2) ? (s - 2) : 0;
      aw1 = wsA[(size_t)i2 * NTAG + lane];
      const int m = mk0;
      mk0 = mk1;
      mk1 = maskb[(s >= 1) ? (s - 1) : 0];
      if (m) {
        const float c = a_cur + transR[lane * 65 + jcur];  // (lane+jcur)%32 banks: conflict-free
        const float cmx = dpp_red_max(c);
        jcur = (int)__builtin_ctzll(__ballot(c == cmx));
      }
      if (lane == 0) tagbuf[s] = jcur;
    }

    for (int t = lane; t < TT; t += 64) {
      const int m = maskb[t];
      out_tags[b * TT + t] = (float)(m ? tagbuf[t] : 0);
    }
  } else {
    // ---------------- log-partition (z-space) + gold ----------------
    __shared__ __align__(16) float zlds[NTAG];
    float ecol[NTAG];  // exp(trans[i][lane])
#pragma unroll
    for (int i = 0; i < NTAG; ++i) ecol[i] = expf(trans[(size_t)i * NTAG + lane]);

    const float alpha0 = startv[lane] + sc[lane];
    const float M0 = dpp_red_max(alpha0);
    float z = expf(alpha0 - M0);  // z = exp(alpha - C)
    float C = M0;                 // lane-uniform scale

    float e0 = sc[1 * NTAG + lane], e1 = sc[2 * NTAG + lane];
    float e2 = sc[3 * NTAG + lane], e3 = sc[4 * NTAG + lane];
    int k0 = maskb[1], k1 = maskb[2], k2 = maskb[3], k3 = maskb[4];
    float pe = expf(e0);  // exp(emission) computed one iter ahead (off critical path)

    for (int t = 1; t < TT; ++t) {
      const float pec = pe;
      const int m = k0;
      const int tp = (t + 4 < TT) ? (t + 4) : (TT - 1);
      e0 = e1; e1 = e2; e2 = e3;
      e3 = sc[(size_t)tp * NTAG + lane];
      k0 = k1; k1 = k2; k2 = k3;
      k3 = maskb[tp];
      pe = expf(e0);  // for t+1; independent of z chain

      zlds[lane] = z;
      float s0 = 0.f, s1 = 0.f, s2 = 0.f, s3 = 0.f;
#pragma unroll
      for (int i = 0; i < NTAG; i += 4) {
        const float4 z4 = *reinterpret_cast<const float4*>(&zlds[i]);
        s0 = fmaf(z4.x, ecol[i + 0], s0);
        s1 = fmaf(z4.y, ecol[i + 1], s1);
        s2 = fmaf(z4.z, ecol[i + 2], s2);
        s3 = fmaf(z4.w, ecol[i + 3], s3);
      }
      const float inner = (s0 + s1) + (s2 + s3);
      z = m ? (inner * pec) : z;

      if ((t & 7) == 0) {  // renormalize; growth <= e^48 per window, safe in fp32
        const float s = dpp_red_sum(z);
        const float r = __builtin_amdgcn_rcpf(s);
        z *= r;
        C += logf(s);  // off critical path
      }
    }
    const float av = logf(z) + C;
    const float fv = av + endv[lane];
    const float M2 = dpp_red_max(fv);
    const float sSum = dpp_red_sum(expf(fv - M2));
    const float log_z = logf(sSum) + M2;

    float g = 0.f, msumf = 0.f;
    for (int t = lane; t < TT; t += 64) {
      const int lab = labels[b * TT + t];
      const float mf = (float)maskb[t];
      msumf += mf;
      g += sc[(size_t)t * NTAG + lab] * mf;
      if (t >= 1) {
        const int labp = labels[b * TT + t - 1];
        g += trans[(size_t)labp * NTAG + lab] * mf;
      }
    }
    g = dpp_red_sum(g);
    const float msum = dpp_red_sum(msumf);
    const int last_idx = (int)msum - 1;
    g += startv[labels[b * TT]] + endv[labels[b * TT + last_idx]];
    if (lane == 0) ws_loss[b] = log_z - g;
  }
}

// ---------------- Kernel 3: loss = mean(log_z - gold) ----------------
__global__ __launch_bounds__(64) void loss_mean(const float* __restrict__ ws_loss,
                                                float* __restrict__ out) {
  const float v = ws_loss[threadIdx.x];
  const float s = dpp_red_sum(v);
  if (threadIdx.x == 0) out[0] = s * (1.0f / 64.0f);
}

extern "C" void kernel_launch(void* const* d_in, const int* in_sizes, int n_in,
                              void* d_out, int out_size, void* d_ws, size_t ws_size,
                              hipStream_t stream) {
  const float* X = (const float*)d_in[0];
  const int* mask = (const int*)d_in[1];
  const int* labels = (const int*)d_in[2];
  const float* W = (const float*)d_in[3];
  const float* bias = (const float*)d_in[4];
  const float* trans = (const float*)d_in[5];
  const float* startv = (const float*)d_in[6];
  const float* endv = (const float*)d_in[7];

  float* out = (float*)d_out;
  float* scores = out;
  float* out_tags = out + TAGS_OFF;
  float* out_loss = out + LOSS_OFF;

  float* ws_alpha = (float*)d_ws;
  float* ws_loss = ws_alpha + (size_t)BB * (TT - 1) * NTAG;

  gemm_scores<<<512, 256, 0, stream>>>(X, mask, W, bias, scores);
  crf_kernel<<<128, 64, 0, stream>>>(scores, mask, labels, trans, startv, endv,
                                     out_tags, ws_alpha, ws_loss);
  loss_mean<<<1, 64, 0, stream>>>(ws_loss, out_loss);
}

// Round 4
// 606.278 us; speedup vs baseline: 1.0490x; 1.0490x over previous
//
#include <hip/hip_runtime.h>
#include <cstdint>
#include <cstddef>

#define BB 64
#define TT 512
#define DD 1024
#define NTAG 64
#define SCORES_ELEMS (BB * TT * NTAG)      // 2097152
#define TAGS_OFF SCORES_ELEMS              // 2097152
#define LOSS_OFF (SCORES_ELEMS + BB * TT)  // 2130920

__device__ __forceinline__ float rl(float v, int i) {
  return __int_as_float(__builtin_amdgcn_readlane(__float_as_int(v), i));
}

// ---------------- DPP wave64 reductions ----------------
__device__ __forceinline__ float dpp_red_max(float v) {
  int x;
  x = __builtin_amdgcn_update_dpp(__float_as_int(v), __float_as_int(v), 0x111, 0xf, 0xf, false);
  v = fmaxf(v, __int_as_float(x));
  x = __builtin_amdgcn_update_dpp(__float_as_int(v), __float_as_int(v), 0x112, 0xf, 0xf, false);
  v = fmaxf(v, __int_as_float(x));
  x = __builtin_amdgcn_update_dpp(__float_as_int(v), __float_as_int(v), 0x114, 0xf, 0xf, false);
  v = fmaxf(v, __int_as_float(x));
  x = __builtin_amdgcn_update_dpp(__float_as_int(v), __float_as_int(v), 0x118, 0xf, 0xf, false);
  v = fmaxf(v, __int_as_float(x));
  x = __builtin_amdgcn_update_dpp(__float_as_int(v), __float_as_int(v), 0x142, 0xa, 0xf, false);
  v = fmaxf(v, __int_as_float(x));
  x = __builtin_amdgcn_update_dpp(__float_as_int(v), __float_as_int(v), 0x143, 0xc, 0xf, false);
  v = fmaxf(v, __int_as_float(x));
  return __int_as_float(__builtin_amdgcn_readlane(__float_as_int(v), 63));
}

__device__ __forceinline__ float dpp_red_sum(float v) {
  int x;
  x = __builtin_amdgcn_update_dpp(__float_as_int(v), __float_as_int(v), 0x111, 0xf, 0xf, false);
  v = v + __int_as_float(x);
  x = __builtin_amdgcn_update_dpp(__float_as_int(v), __float_as_int(v), 0x112, 0xf, 0xf, false);
  v = v + __int_as_float(x);
  x = __builtin_amdgcn_update_dpp(__float_as_int(v), __float_as_int(v), 0x114, 0xf, 0xf, false);
  v = v + __int_as_float(x);
  x = __builtin_amdgcn_update_dpp(__float_as_int(v), __float_as_int(v), 0x118, 0xf, 0xf, false);
  v = v + __int_as_float(x);
  x = __builtin_amdgcn_update_dpp(__float_as_int(v), __float_as_int(v), 0x142, 0xa, 0xf, false);
  v = v + __int_as_float(x);
  x = __builtin_amdgcn_update_dpp(__float_as_int(v), __float_as_int(v), 0x143, 0xc, 0xf, false);
  v = v + __int_as_float(x);
  return __int_as_float(__builtin_amdgcn_readlane(__float_as_int(v), 63));
}

// ---------------- Kernel 1: scores = (X @ W + b) * mask ----------------
// 512 blocks x 256 thr, tile 64x64, waves split K 4-ways (no main-loop
// barriers). launch_bounds(256,2): VGPR cap 256 so the 64-reg accumulator
// + 32 prefetch regs never spill.
__global__ __launch_bounds__(256, 2) void gemm_scores(
    const float* __restrict__ X, const int* __restrict__ mask,
    const float* __restrict__ W, const float* __restrict__ bias,
    float* __restrict__ scores) {
  __shared__ float smem[12288];  // [0,8192) wave staging (2048/wave), [8192,12288) psum
  const int tid = threadIdx.x;
  const int lane = tid & 63;
  const int wv = tid >> 6;
  const int row0 = blockIdx.x * 64;
  const int kbase = wv * 256;
  float* psum = smem + 8192;

  {
    const float4 z4 = make_float4(0.f, 0.f, 0.f, 0.f);
#pragma unroll
    for (int g = 0; g < 4; ++g)
      *reinterpret_cast<float4*>(&psum[tid * 16 + g * 4]) = z4;
  }
  __syncthreads();

  float* smx = smem + wv * 2048;         // xT[16][64]: smx[k*64+row]
  float* smw = smem + wv * 2048 + 1024;  // wt[16][64]: smw[k*64+col]

  const int lr = lane & 7;
  const int lc = lane >> 3;
  const int xrow = lane >> 2;      // 0..15
  const int xkk = (lane & 3) * 4;  // 0,4,8,12

  float acc[8][8];
#pragma unroll
  for (int i = 0; i < 8; ++i)
#pragma unroll
    for (int j = 0; j < 8; ++j) acc[i][j] = 0.f;

  const float* Xb = X + (size_t)row0 * DD + kbase;
  const float* Wb = W + (size_t)kbase * NTAG;

  float4 px[4], pw[4];
#pragma unroll
  for (int p = 0; p < 4; ++p) {
    px[p] = *reinterpret_cast<const float4*>(Xb + (size_t)(xrow + p * 16) * DD + xkk);
    pw[p] = *reinterpret_cast<const float4*>(Wb + p * 256 + lane * 4);
  }

  for (int c = 0; c < 16; ++c) {
#pragma unroll
    for (int p = 0; p < 4; ++p) {
      const int r = xrow + p * 16;
      smx[(xkk + 0) * 64 + r] = px[p].x;
      smx[(xkk + 1) * 64 + r] = px[p].y;
      smx[(xkk + 2) * 64 + r] = px[p].z;
      smx[(xkk + 3) * 64 + r] = px[p].w;
      *reinterpret_cast<float4*>(&smw[p * 256 + lane * 4]) = pw[p];
    }
    const int cn = (c < 15) ? (c + 1) : 0;
#pragma unroll
    for (int p = 0; p < 4; ++p) {
      px[p] = *reinterpret_cast<const float4*>(
          Xb + (size_t)(xrow + p * 16) * DD + cn * 16 + xkk);
      pw[p] = *reinterpret_cast<const float4*>(Wb + cn * 1024 + p * 256 + lane * 4);
    }
#pragma unroll
    for (int k = 0; k < 16; ++k) {
      const float4 xa = *reinterpret_cast<const float4*>(&smx[k * 64 + lr * 8]);
      const float4 xb2 = *reinterpret_cast<const float4*>(&smx[k * 64 + lr * 8 + 4]);
      const float4 wa = *reinterpret_cast<const float4*>(&smw[k * 64 + lc * 8]);
      const float4 wb2 = *reinterpret_cast<const float4*>(&smw[k * 64 + lc * 8 + 4]);
      const float x0 = xa.x, x1 = xa.y, x2 = xa.z, x3 = xa.w;
      const float x4 = xb2.x, x5 = xb2.y, x6 = xb2.z, x7 = xb2.w;
      const float q0 = wa.x, q1 = wa.y, q2 = wa.z, q3 = wa.w;
      const float q4 = wb2.x, q5 = wb2.y, q6 = wb2.z, q7 = wb2.w;
#define ROW(i, xi)                                                   \
  acc[i][0] = fmaf(xi, q0, acc[i][0]); acc[i][1] = fmaf(xi, q1, acc[i][1]); \
  acc[i][2] = fmaf(xi, q2, acc[i][2]); acc[i][3] = fmaf(xi, q3, acc[i][3]); \
  acc[i][4] = fmaf(xi, q4, acc[i][4]); acc[i][5] = fmaf(xi, q5, acc[i][5]); \
  acc[i][6] = fmaf(xi, q6, acc[i][6]); acc[i][7] = fmaf(xi, q7, acc[i][7]);
      ROW(0, x0) ROW(1, x1) ROW(2, x2) ROW(3, x3)
      ROW(4, x4) ROW(5, x5) ROW(6, x6) ROW(7, x7)
#undef ROW
    }
  }

#pragma unroll
  for (int i = 0; i < 8; ++i) {
    const int row = lr * 8 + i;
#pragma unroll
    for (int j = 0; j < 8; ++j)
      atomicAdd(&psum[row * 64 + lc * 8 + j], acc[i][j]);
  }
  __syncthreads();

  const int f = tid * 16;
  const int row = f >> 6;
  const float mf = (float)mask[row0 + row];
#pragma unroll
  for (int g = 0; g < 4; ++g) {
    const int idx = f + g * 4;
    const int col = idx & 63;
    const float4 p = *reinterpret_cast<float4*>(&psum[idx]);
    const float4 b4 = *reinterpret_cast<const float4*>(&bias[col]);
    float4 o;
    o.x = (p.x + b4.x) * mf;
    o.y = (p.y + b4.y) * mf;
    o.z = (p.z + b4.z) * mf;
    o.w = (p.w + b4.w) * mf;
    *reinterpret_cast<float4*>(&scores[(size_t)(row0 + row) * 64 + col]) = o;
  }
}

// ---------------- Kernel 2: forward passes (no LDS; readlane broadcast) ----
// Blocks [0,64): viterbi forward (max only) -> alpha history + last tag.
// Blocks [64,128): z-space log-partition + gold score.
__global__ __launch_bounds__(64) void crf_forward(
    const float* __restrict__ scores, const int* __restrict__ mask,
    const int* __restrict__ labels, const float* __restrict__ trans,
    const float* __restrict__ startv, const float* __restrict__ endv,
    float* __restrict__ ws_alpha, int* __restrict__ ws_lasttag,
    float* __restrict__ ws_loss) {
  const int lane = threadIdx.x;
  const int role = blockIdx.x >> 6;
  const int b = blockIdx.x & 63;
  const float* sc = scores + (size_t)b * TT * NTAG;
  const int* maskb = mask + b * TT;

  if (role == 0) {
    float tcol[NTAG];  // tcol[i] = trans[i][lane]
#pragma unroll
    for (int i = 0; i < NTAG; ++i) tcol[i] = trans[(size_t)i * NTAG + lane];
    float valpha = startv[lane] + sc[lane];
    float* wsA = ws_alpha + (size_t)b * (TT - 1) * NTAG;

    float e0 = sc[1 * NTAG + lane], e1 = sc[2 * NTAG + lane];
    float e2 = sc[3 * NTAG + lane], e3 = sc[4 * NTAG + lane];
    int k0 = maskb[1], k1 = maskb[2], k2 = maskb[3], k3 = maskb[4];

    for (int t = 1; t < TT; ++t) {
      wsA[(size_t)(t - 1) * NTAG + lane] = valpha;
      const float emit = e0;
      const int m = k0;
      const int tp = (t + 4 < TT) ? (t + 4) : (TT - 1);
      e0 = e1; e1 = e2; e2 = e3;
      e3 = sc[(size_t)tp * NTAG + lane];
      k0 = k1; k1 = k2; k2 = k3;
      k3 = maskb[tp];

      float m0 = -3.4e38f, m1 = -3.4e38f, m2 = -3.4e38f, m3 = -3.4e38f;
#pragma unroll
      for (int i = 0; i < NTAG; i += 4) {
        m0 = fmaxf(m0, rl(valpha, i + 0) + tcol[i + 0]);
        m1 = fmaxf(m1, rl(valpha, i + 1) + tcol[i + 1]);
        m2 = fmaxf(m2, rl(valpha, i + 2) + tcol[i + 2]);
        m3 = fmaxf(m3, rl(valpha, i + 3) + tcol[i + 3]);
      }
      const float best = fmaxf(fmaxf(m0, m1), fmaxf(m2, m3));
      valpha = m ? (best + emit) : valpha;
    }

    const float fin = valpha + endv[lane];
    const float mx = dpp_red_max(fin);
    const int jlast = (int)__builtin_ctzll(__ballot(fin == mx));
    if (lane == 0) ws_lasttag[b] = jlast;
  } else {
    float ecol[NTAG];  // exp(trans[i][lane])
#pragma unroll
    for (int i = 0; i < NTAG; ++i) ecol[i] = expf(trans[(size_t)i * NTAG + lane]);

    const float alpha0 = startv[lane] + sc[lane];
    const float M0 = dpp_red_max(alpha0);
    float z = expf(alpha0 - M0);  // z = exp(alpha - C)
    float C = M0;

    float e0 = sc[1 * NTAG + lane], e1 = sc[2 * NTAG + lane];
    float e2 = sc[3 * NTAG + lane], e3 = sc[4 * NTAG + lane];
    int k0 = maskb[1], k1 = maskb[2], k2 = maskb[3], k3 = maskb[4];
    float pe = expf(e0);

    for (int t = 1; t < TT; ++t) {
      const float pec = pe;
      const int m = k0;
      const int tp = (t + 4 < TT) ? (t + 4) : (TT - 1);
      e0 = e1; e1 = e2; e2 = e3;
      e3 = sc[(size_t)tp * NTAG + lane];
      k0 = k1; k1 = k2; k2 = k3;
      k3 = maskb[tp];
      pe = expf(e0);  // off critical path

      float s0 = 0.f, s1 = 0.f, s2 = 0.f, s3 = 0.f;
#pragma unroll
      for (int i = 0; i < NTAG; i += 4) {
        s0 = fmaf(rl(z, i + 0), ecol[i + 0], s0);
        s1 = fmaf(rl(z, i + 1), ecol[i + 1], s1);
        s2 = fmaf(rl(z, i + 2), ecol[i + 2], s2);
        s3 = fmaf(rl(z, i + 3), ecol[i + 3], s3);
      }
      const float inner = (s0 + s1) + (s2 + s3);
      z = m ? (inner * pec) : z;

      if ((t & 7) == 0) {  // renormalize; growth bounded, fp32-safe
        const float s = dpp_red_sum(z);
        const float r = __builtin_amdgcn_rcpf(s);
        z *= r;
        C += logf(s);
      }
    }
    const float av = logf(z) + C;
    const float fv = av + endv[lane];
    const float M2 = dpp_red_max(fv);
    const float sSum = dpp_red_sum(expf(fv - M2));
    const float log_z = logf(sSum) + M2;

    float g = 0.f, msumf = 0.f;
    for (int t = lane; t < TT; t += 64) {
      const int lab = labels[b * TT + t];
      const float mf = (float)maskb[t];
      msumf += mf;
      g += sc[(size_t)t * NTAG + lab] * mf;
      if (t >= 1) {
        const int labp = labels[b * TT + t - 1];
        g += trans[(size_t)labp * NTAG + lab] * mf;
      }
    }
    g = dpp_red_sum(g);
    const float msum = dpp_red_sum(msumf);
    const int last_idx = (int)msum - 1;
    g += startv[labels[b * TT]] + endv[labels[b * TT + last_idx]];
    if (lane == 0) ws_loss[b] = log_z - g;
  }
}

// ---------------- Kernel 3: parallel backpointers + serial chase ----------
// 64 blocks (one per batch) x 256 thr. 4 waves compute bp[t][j] for all t in
// parallel (adds bit-identical to forward; ascending strict-> scan = first-
// occurrence argmax like jnp.argmax). Then one lane chases 511 LDS reads.
__global__ __launch_bounds__(256) void viterbi_bt(
    const float* __restrict__ ws_alpha, const int* __restrict__ ws_lasttag,
    const int* __restrict__ mask, const float* __restrict__ trans,
    float* __restrict__ out_tags) {
  __shared__ unsigned char bp_lds[(TT - 1) * NTAG];  // 32704 B
  __shared__ int mk[TT];
  __shared__ unsigned char tagb[TT];
  const int tid = threadIdx.x;
  const int lane = tid & 63;
  const int wv = tid >> 6;
  const int b = blockIdx.x;

  float tcol[NTAG];
#pragma unroll
  for (int i = 0; i < NTAG; ++i) tcol[i] = trans[(size_t)i * NTAG + lane];
  for (int t = tid; t < TT; t += 256) mk[t] = mask[b * TT + t];

  const float* wsA = ws_alpha + (size_t)b * (TT - 1) * NTAG;
  for (int s = wv; s < TT - 1; s += 4) {
    const float av = wsA[(size_t)s * NTAG + lane];
    float best = rl(av, 0) + tcol[0];
    int bi = 0;
#pragma unroll
    for (int i = 1; i < NTAG; ++i) {
      const float c = rl(av, i) + tcol[i];
      bi = (c > best) ? i : bi;
      best = fmaxf(c, best);
    }
    bp_lds[s * NTAG + lane] = (unsigned char)bi;
  }
  __syncthreads();

  if (tid == 0) {
    int jcur = ws_lasttag[b];
    tagb[TT - 1] = (unsigned char)jcur;
    for (int s = TT - 2; s >= 0; --s) {
      if (mk[s + 1]) jcur = bp_lds[s * NTAG + jcur];
      tagb[s] = (unsigned char)jcur;
    }
  }
  __syncthreads();

  for (int t = tid; t < TT; t += 256)
    out_tags[b * TT + t] = (float)(mk[t] ? (int)tagb[t] : 0);
}

// ---------------- Kernel 4: loss = mean(log_z - gold) ----------------
__global__ __launch_bounds__(64) void loss_mean(const float* __restrict__ ws_loss,
                                                float* __restrict__ out) {
  const float v = ws_loss[threadIdx.x];
  const float s = dpp_red_sum(v);
  if (threadIdx.x == 0) out[0] = s * (1.0f / 64.0f);
}

extern "C" void kernel_launch(void* const* d_in, const int* in_sizes, int n_in,
                              void* d_out, int out_size, void* d_ws, size_t ws_size,
                              hipStream_t stream) {
  const float* X = (const float*)d_in[0];
  const int* mask = (const int*)d_in[1];
  const int* labels = (const int*)d_in[2];
  const float* W = (const float*)d_in[3];
  const float* bias = (const float*)d_in[4];
  const float* trans = (const float*)d_in[5];
  const float* startv = (const float*)d_in[6];
  const float* endv = (const float*)d_in[7];

  float* out = (float*)d_out;
  float* scores = out;
  float* out_tags = out + TAGS_OFF;
  float* out_loss = out + LOSS_OFF;

  float* ws_alpha = (float*)d_ws;  // 64*511*64 floats = 8.37 MB
  int* ws_lasttag = (int*)(ws_alpha + (size_t)BB * (TT - 1) * NTAG);
  float* ws_loss = (float*)(ws_lasttag + BB);

  gemm_scores<<<512, 256, 0, stream>>>(X, mask, W, bias, scores);
  crf_forward<<<128, 64, 0, stream>>>(scores, mask, labels, trans, startv, endv,
                                      ws_alpha, ws_lasttag, ws_loss);
  viterbi_bt<<<64, 256, 0, stream>>>(ws_alpha, ws_lasttag, mask, trans, out_tags);
  loss_mean<<<1, 64, 0, stream>>>(ws_loss, out_loss);
}